// Round 7
// baseline (414.886 us; speedup 1.0000x reference)
//
#include <hip/hip_runtime.h>

typedef unsigned short u16;
typedef __bf16 bf16x8 __attribute__((ext_vector_type(8)));
typedef float f32x4 __attribute__((ext_vector_type(4)));
typedef u16 u16x8 __attribute__((ext_vector_type(8)));

static constexpr int kNRoi = 2000;
static constexpr int kMPad = 2048;
static constexpr int kKin  = 12544;
static constexpr int kHid  = 1024;
static constexpr int kNOutPad = 512;
static constexpr int kNC = 81;
static constexpr int kND = 324;

// Measured facts (rounds 2-6): inputs f32, outputs f32. b1/b2 cancelled by
// train-mode BN. GEMM1 plateau 113us with A1-bf16 path; prep ~245MB was #2.

__device__ __forceinline__ u16 f2bf(float f) {
  union { float f; unsigned u; } v; v.f = f;
  unsigned r = v.u + 0x7fffu + ((v.u >> 16) & 1u);   // RNE, finite inputs only
  return (u16)(r >> 16);
}

__device__ __forceinline__ bf16x8 cvt8(f32x4 lo, f32x4 hi) {
  bf16x8 r;
#pragma unroll
  for (int j = 0; j < 4; ++j) { r[j] = (__bf16)lo[j]; r[4 + j] = (__bf16)hi[j]; }
  return r;
}

// ---- device transpose helpers ----------------------------------------------
__device__ __forceinline__ void transpose64(const float* __restrict__ in,
                                            u16* __restrict__ out, int R, int C,
                                            int bx, int by, u16* t, int tid) {
  const int cb = bx * 64, rb = by * 64;
  const int rl = tid >> 4, cl = (tid & 15) * 4;
#pragma unroll
  for (int i = 0; i < 4; ++i) {
    int r = rl + i * 16;
    f32x4 v = *(const f32x4*)(in + (long)(rb + r) * C + cb + cl);
#pragma unroll
    for (int j = 0; j < 4; ++j) t[(cl + j) * 72 + r] = f2bf(v[j]);
  }
  __syncthreads();
  const int c2 = tid >> 3, r2 = (tid & 7) * 8;
#pragma unroll
  for (int i = 0; i < 2; ++i) {
    int c = c2 + i * 32;
    u16x8 v = *(const u16x8*)&t[c * 72 + r2];
    *(u16x8*)(out + (long)(cb + c) * R + rb + r2) = v;
  }
}

__device__ __forceinline__ void transpose32(const float* __restrict__ in,
                                            u16* __restrict__ out, int R, int C,
                                            int bx, int by, u16* t, int tid) {
  int tx = tid & 31, ty = tid >> 5;
  int cb = bx * 32, rb = by * 32;
#pragma unroll
  for (int i = 0; i < 4; ++i) {
    int r = rb + ty + i * 8, c = cb + tx;
    if (r < R && c < C) t[(ty + i * 8) * 33 + tx] = f2bf(in[(long)r * C + c]);
  }
  __syncthreads();
#pragma unroll
  for (int i = 0; i < 4; ++i) {
    int c = cb + ty + i * 8, r = rb + tx;
    if (c < C && r < R) out[(long)c * R + r] = t[tx * 33 + ty + i * 8];
  }
}

// ---- fused prep: weight transposes + zero-init (no A traffic) --------------
// grid = 3136 + 256 + 96 + 352 + 54 + 2048 + 4 = 5946 blocks of 256
__global__ __launch_bounds__(256) void prep(
    const float* __restrict__ w1, const float* __restrict__ w2,
    const float* __restrict__ wl, const float* __restrict__ wd,
    u16* __restrict__ W1T, u16* __restrict__ W2T, u16* __restrict__ WHT,
    float* __restrict__ X1, float* __restrict__ S) {
  __shared__ u16 sh[64 * 72];
  const int tid = threadIdx.x;
  int id = blockIdx.x;
  if (id < 3136) { transpose64(w1, W1T, kKin, kHid, id & 15, id >> 4, sh, tid); return; }
  id -= 3136;
  if (id < 256)  { transpose64(w2, W2T, kHid, kHid, id & 15, id >> 4, sh, tid); return; }
  id -= 256;
  if (id < 96)   { transpose32(wl, WHT, kHid, kNC, id % 3, id / 3, sh, tid); return; }
  id -= 96;
  if (id < 352)  { transpose32(wd, WHT + kNC * kHid, kHid, kND, id % 11, id / 11, sh, tid); return; }
  id -= 352;
  if (id < 54) {                          // zero WHT rows 405..511 (pad)
    int idx = id * 256 + tid;             // u16x8 units; 107*1024/8 = 13696
    if (idx < 13696) *(u16x8*)(WHT + 405 * kHid + idx * 8) = (u16x8){};
    return;
  }
  id -= 54;
  if (id < 2048) {                        // zero X1
    *(f32x4*)(X1 + ((long)id * 256 + tid) * 4) = (f32x4){};
    return;
  }
  id -= 2048;                             // zero S1/SS1/S2/SS2
  *(f32x4*)(S + ((long)id * 256 + tid) * 4) = (f32x4){};
}

// ---- GEMM1: C += A_f32[M][K] * Bt_bf16[N][K]^T, split-K atomics ------------
// A staged as raw f32 via global_load_lds with XOR-swizzled source addresses:
// LDS granule (16B) index r*8 + (j ^ (r&7)) holds global granule j of row r.
// Frag reads land 2-way-conflict-free; cvt f32->bf16 at frag-read time.
__global__ __launch_bounds__(256) void gemm1_f32a(
    const float* __restrict__ A, const u16* __restrict__ Bt,
    float* __restrict__ C, int Mreal, int K, int N, int kchunk) {
  __shared__ float As[2][4096];   // 128 rows x 8 granules x 4 f32 = 16 KB
  __shared__ u16   Bs[2][4096];   // 128 rows x 32 bf16 = 8 KB
  const int tid  = threadIdx.x;
  const int lane = tid & 63;
  const int wave = tid >> 6;
  const int wm = (wave >> 1) * 64;
  const int wn = (wave & 1) * 64;

  f32x4 acc[4][4] = {};

  const int kb = blockIdx.z * kchunk;

  // A staging: instr i (0..3), wave w, lane l -> row 32i+8w+(l>>3),
  // src granule jsrc = (l&7) ^ (l>>3), LDS slot = linear (i*256+w*64+l).
  const int dr   = lane >> 3;           // 0..7
  const int jsrc = (lane & 7) ^ dr;     // swizzled source granule
  const float* pA[4];
#pragma unroll
  for (int i = 0; i < 4; ++i) {
    long r = (long)blockIdx.x * 128 + 32 * i + 8 * wave + dr;
    if (r > Mreal - 1) r = Mreal - 1;
    pA[i] = A + r * K + kb + jsrc * 4;
  }

  // B staging: thread tid -> row tid>>2, kofs (tid&3)*8 (elem tid*8 in LDS)
  const int r0 = tid >> 2;
  const int kc = (tid & 3) * 8;
  const long br0 = (long)blockIdx.y * 128 + r0;
  const u16* bg0 = Bt + br0 * K + kb + kc;
  const u16* bg1 = Bt + (br0 + 64) * K + kb + kc;

  const int fr = lane & 15;
  const int fq = (lane >> 4) * 8;       // k offset within 32
  const int j0 = (lane >> 4) * 2;       // first f32 granule of the frag
  const int iters = kchunk / 32;

#define STAGE(b) do {                                                          \
    _Pragma("unroll")                                                          \
    for (int i_ = 0; i_ < 4; ++i_) {                                           \
      __builtin_amdgcn_global_load_lds(                                        \
        (const __attribute__((address_space(1))) void*)pA[i_],                 \
        (__attribute__((address_space(3))) void*)&As[b][(i_ * 256 + wave * 64) * 4], 16, 0, 0); \
      pA[i_] += 32;                                                            \
    }                                                                          \
    u16* bl_ = Bs[b] + wave * 512;                                             \
    __builtin_amdgcn_global_load_lds((const __attribute__((address_space(1))) void*)bg0, \
                                     (__attribute__((address_space(3))) void*)bl_, 16, 0, 0); \
    __builtin_amdgcn_global_load_lds((const __attribute__((address_space(1))) void*)bg1, \
                                     (__attribute__((address_space(3))) void*)(bl_ + 2048), 16, 0, 0); \
    bg0 += 32; bg1 += 32;                                                      \
  } while (0)

  STAGE(0);
  int buf = 0;
  for (int it = 0; it < iters; ++it) {
    __syncthreads();
    if (it + 1 < iters) STAGE(buf ^ 1);

    const float* as_ = As[buf];
    const u16*   bs_ = Bs[buf];
    bf16x8 afr[4], bfr[4];
#pragma unroll
    for (int i = 0; i < 4; ++i) {
      int r = wm + i * 16 + fr;
      int g0 = r * 8 + (j0 ^ (fr & 7));
      f32x4 lo = *(const f32x4*)(as_ + g0 * 4);
      f32x4 hi = *(const f32x4*)(as_ + (g0 ^ 1) * 4);
      afr[i] = cvt8(lo, hi);
    }
#pragma unroll
    for (int i = 0; i < 4; ++i)
      bfr[i] = *(const bf16x8*)(bs_ + (wn + i * 16 + fr) * 32 + fq);
#pragma unroll
    for (int mi = 0; mi < 4; ++mi)
#pragma unroll
      for (int ni = 0; ni < 4; ++ni)
        acc[mi][ni] = __builtin_amdgcn_mfma_f32_16x16x32_bf16(afr[mi], bfr[ni], acc[mi][ni], 0, 0, 0);
    buf ^= 1;
  }
#undef STAGE

  const int row0 = blockIdx.x * 128 + wm + (lane >> 4) * 4;
  const int col0 = blockIdx.y * 128 + wn + fr;
#pragma unroll
  for (int mi = 0; mi < 4; ++mi)
#pragma unroll
    for (int ni = 0; ni < 4; ++ni)
#pragma unroll
      for (int e = 0; e < 4; ++e)
        atomicAdd(&C[(long)(row0 + mi * 16 + e) * N + col0 + ni * 16], acc[mi][ni][e]);
}

// ---- bf16 GEMM (GEMM2/3): C += A_bf16 @ Bt^T, split-K atomics --------------
__global__ __launch_bounds__(256) void gemm_bt(
    const u16* __restrict__ A, const u16* __restrict__ Bt,
    float* __restrict__ C, int Mreal, int K, int N, int kchunk) {
  __shared__ u16 As[2][128 * 32];
  __shared__ u16 Bs[2][128 * 32];
  const int tid  = threadIdx.x;
  const int lane = tid & 63;
  const int wave = tid >> 6;
  const int wm = (wave >> 1) * 64;
  const int wn = (wave & 1) * 64;

  f32x4 acc[4][4] = {};

  const int r0 = tid >> 2;
  const int kc = (tid & 3) * 8;
  long ar0 = (long)blockIdx.x * 128 + r0;      if (ar0 > Mreal - 1) ar0 = Mreal - 1;
  long ar1 = (long)blockIdx.x * 128 + 64 + r0; if (ar1 > Mreal - 1) ar1 = Mreal - 1;
  const long br0 = (long)blockIdx.y * 128 + r0;
  const long br1 = br0 + 64;

  const int kb = blockIdx.z * kchunk;
  const u16* ag0 = A + ar0 * K + kb + kc;
  const u16* ag1 = A + ar1 * K + kb + kc;
  const u16* bg0 = Bt + br0 * K + kb + kc;
  const u16* bg1 = Bt + br1 * K + kb + kc;

  const int fr = lane & 15;
  const int fq = (lane >> 4) * 8;
  const int iters = kchunk / 32;

#define STAGE(b) do {                                                          \
    u16* al_ = As[b] + wave * 512;                                             \
    u16* bl_ = Bs[b] + wave * 512;                                             \
    __builtin_amdgcn_global_load_lds((const __attribute__((address_space(1))) void*)ag0, \
                                     (__attribute__((address_space(3))) void*)al_, 16, 0, 0); \
    __builtin_amdgcn_global_load_lds((const __attribute__((address_space(1))) void*)ag1, \
                                     (__attribute__((address_space(3))) void*)(al_ + 2048), 16, 0, 0); \
    __builtin_amdgcn_global_load_lds((const __attribute__((address_space(1))) void*)bg0, \
                                     (__attribute__((address_space(3))) void*)bl_, 16, 0, 0); \
    __builtin_amdgcn_global_load_lds((const __attribute__((address_space(1))) void*)bg1, \
                                     (__attribute__((address_space(3))) void*)(bl_ + 2048), 16, 0, 0); \
    ag0 += 32; ag1 += 32; bg0 += 32; bg1 += 32;                                \
  } while (0)

  STAGE(0);
  int buf = 0;
  for (int it = 0; it < iters; ++it) {
    __syncthreads();
    if (it + 1 < iters) STAGE(buf ^ 1);

    const u16* as_ = As[buf];
    const u16* bs_ = Bs[buf];
    bf16x8 afr[4], bfr[4];
#pragma unroll
    for (int i = 0; i < 4; ++i)
      afr[i] = *(const bf16x8*)(as_ + (wm + i * 16 + fr) * 32 + fq);
#pragma unroll
    for (int i = 0; i < 4; ++i)
      bfr[i] = *(const bf16x8*)(bs_ + (wn + i * 16 + fr) * 32 + fq);
#pragma unroll
    for (int mi = 0; mi < 4; ++mi)
#pragma unroll
      for (int ni = 0; ni < 4; ++ni)
        acc[mi][ni] = __builtin_amdgcn_mfma_f32_16x16x32_bf16(afr[mi], bfr[ni], acc[mi][ni], 0, 0, 0);
    buf ^= 1;
  }
#undef STAGE

  const int row0 = blockIdx.x * 128 + wm + (lane >> 4) * 4;
  const int col0 = blockIdx.y * 128 + wn + fr;
#pragma unroll
  for (int mi = 0; mi < 4; ++mi)
#pragma unroll
    for (int ni = 0; ni < 4; ++ni)
#pragma unroll
      for (int e = 0; e < 4; ++e)
        atomicAdd(&C[(long)(row0 + mi * 16 + e) * N + col0 + ni * 16], acc[mi][ni][e]);
}

// ---- colstats over first 2000 rows + optional zeroing ----------------------
__global__ __launch_bounds__(256) void colstats_zero(
    const float* __restrict__ X, float* __restrict__ S, float* __restrict__ SS,
    float* __restrict__ Z) {
  int id = blockIdx.x;
  if (id < 320) {
    int c = (id & 3) * 256 + threadIdx.x;
    int r0 = (id >> 2) * 25;
    float s = 0.f, ss = 0.f;
    for (int r = r0; r < r0 + 25; ++r) {
      float v = X[(long)r * kHid + c];
      s += v; ss += v * v;
    }
    atomicAdd(&S[c], s);
    atomicAdd(&SS[c], ss);
  } else {
    id -= 320;
    *(f32x4*)(Z + ((long)id * 256 + threadIdx.x) * 4) = (f32x4){};
  }
}

// ---- BN(train) + ReLU + bf16 cast ------------------------------------------
__global__ __launch_bounds__(256) void bn_relu(
    const float* __restrict__ X, const float* __restrict__ S,
    const float* __restrict__ SS, const float* __restrict__ gamma,
    const float* __restrict__ beta, u16* __restrict__ H) {
  constexpr float invN = 1.f / (float)kNRoi;
  long i = ((long)blockIdx.x * 256 + threadIdx.x) * 8;
  int c = (int)(i & (kHid - 1));
  f32x4 x0 = *(const f32x4*)(X + i);
  f32x4 x1 = *(const f32x4*)(X + i + 4);
  f32x4 s0 = *(const f32x4*)(S + c),    s1 = *(const f32x4*)(S + c + 4);
  f32x4 q0 = *(const f32x4*)(SS + c),   q1 = *(const f32x4*)(SS + c + 4);
  f32x4 g0 = *(const f32x4*)(gamma + c), g1 = *(const f32x4*)(gamma + c + 4);
  f32x4 b0 = *(const f32x4*)(beta + c),  b1 = *(const f32x4*)(beta + c + 4);
  u16x8 h;
#pragma unroll
  for (int j = 0; j < 4; ++j) {
    float mu = s0[j] * invN;
    float var = q0[j] * invN - mu * mu;
    float sc = g0[j] * rsqrtf(var + 1e-3f);
    h[j] = f2bf(fmaxf(0.f, sc * x0[j] + (b0[j] - mu * sc)));
    mu = s1[j] * invN;
    var = q1[j] * invN - mu * mu;
    sc = g1[j] * rsqrtf(var + 1e-3f);
    h[4 + j] = f2bf(fmaxf(0.f, sc * x1[j] + (b1[j] - mu * sc)));
  }
  *(u16x8*)(H + i) = h;
}

// ---- bias + softmax + f32 outputs, one wave per row ------------------------
__global__ __launch_bounds__(256) void head_out(
    const float* __restrict__ X, const float* __restrict__ bl,
    const float* __restrict__ bd, float* __restrict__ out) {
  int lane = threadIdx.x & 63;
  int row = blockIdx.x * 4 + (threadIdx.x >> 6);
  if (row >= kNRoi) return;
  const float* xr = X + (long)row * kNOutPad;
  float v0 = xr[lane] + bl[lane];
  float v1 = (lane < kNC - 64) ? xr[64 + lane] + bl[64 + lane] : -3.0e38f;
  float m = fmaxf(v0, v1);
#pragma unroll
  for (int off = 32; off > 0; off >>= 1) m = fmaxf(m, __shfl_xor(m, off, 64));
  float e0 = __expf(v0 - m);
  float e1 = (lane < kNC - 64) ? __expf(v1 - m) : 0.f;
  float s = e0 + e1;
#pragma unroll
  for (int off = 32; off > 0; off >>= 1) s += __shfl_xor(s, off, 64);
  float inv = 1.f / s;
  float* lo = out + (long)row * kNC;
  float* pr = out + (long)kNRoi * kNC + (long)row * kNC;
  float* de = out + 2L * kNRoi * kNC + (long)row * kND;
  lo[lane] = v0;
  pr[lane] = e0 * inv;
  if (lane < kNC - 64) { lo[64 + lane] = v1; pr[64 + lane] = e1 * inv; }
#pragma unroll
  for (int j = 0; j < 5; ++j) {
    int c = lane + 64 * j;
    de[c] = xr[kNC + c] + bd[c];
  }
  if (lane < 4) { int c = lane + 320; de[c] = xr[kNC + c] + bd[c]; }
}

// ---- launch ----------------------------------------------------------------
extern "C" void kernel_launch(void* const* d_in, const int* in_sizes, int n_in,
                              void* d_out, int out_size, void* d_ws, size_t ws_size,
                              hipStream_t stream) {
  const float* pooled   = (const float*)d_in[0];
  const float* w1       = (const float*)d_in[1];
  const float* gamma1   = (const float*)d_in[3];
  const float* beta1    = (const float*)d_in[4];
  const float* w2       = (const float*)d_in[5];
  const float* gamma2   = (const float*)d_in[7];
  const float* beta2    = (const float*)d_in[8];
  const float* w_logits = (const float*)d_in[9];
  const float* b_logits = (const float*)d_in[10];
  const float* w_delta  = (const float*)d_in[11];
  const float* b_delta  = (const float*)d_in[12];

  char* ws = (char*)d_ws;
  u16*   W1T  = (u16*)(ws + 0);            // [1024][12544] bf16
  u16*   W2T  = (u16*)(ws + 25690112);     // [1024][1024]  bf16
  u16*   WHT  = (u16*)(ws + 27787264);     // [512][1024]   bf16 (rows 405..511 zero)
  float* X1   = (float*)(ws + 28835840);   // [2048][1024] f32
  u16*   H    = (u16*)(ws + 37224448);     // [2048][1024] bf16 (H1 then H2)
  float* S    = (float*)(ws + 41418752);   // S1|SS1|S2|SS2, 4x1024 f32
  float* X2   = (float*)(ws + 41435136);   // [2048][1024] f32
  float* XOUT = (float*)(ws + 49823744);   // [2048][512]  f32

  float* S1  = S;
  float* SS1 = S + 1024;
  float* S2  = S + 2048;
  float* SS2 = S + 3072;

  // 1) prep: weight transposes + zero X1/S/WHT-pad (no pooled traffic)
  prep<<<5946, 256, 0, stream>>>(w1, w2, w_logits, w_delta, W1T, W2T, WHT, X1, S);

  // 2) GEMM1: X1 += pooled(f32) @ W1T^T   (split-K 8: 1024 blocks, 49 iters)
  gemm1_f32a<<<dim3(16, 8, 8), 256, 0, stream>>>(pooled, W1T, X1, kNRoi, kKin, kHid, kKin / 8);

  // 3) BN1 stats + zero X2/XOUT
  colstats_zero<<<320 + 3072, 256, 0, stream>>>(X1, S1, SS1, X2);
  bn_relu<<<(kMPad * kHid) / 2048, 256, 0, stream>>>(X1, S1, SS1, gamma1, beta1, H);

  // 4) GEMM2: X2 += H @ W2T^T   (split-K 4: 512 blocks, 8 iters)
  gemm_bt<<<dim3(16, 8, 4), 256, 0, stream>>>(H, W2T, X2, kMPad, kHid, kHid, kHid / 4);

  // 5) BN2 stats + apply
  colstats_zero<<<320, 256, 0, stream>>>(X2, S2, SS2, nullptr);
  bn_relu<<<(kMPad * kHid) / 2048, 256, 0, stream>>>(X2, S2, SS2, gamma2, beta2, H);

  // 6) GEMM3: XOUT += H @ WHT^T  (split-K 4: 256 blocks, 8 iters)
  gemm_bt<<<dim3(16, 4, 4), 256, 0, stream>>>(H, WHT, XOUT, kMPad, kHid, kNOutPad, kHid / 4);

  // 7) bias + softmax + f32 outputs
  head_out<<<kNRoi / 4, 256, 0, stream>>>(XOUT, b_logits, b_delta, (float*)d_out);
}